// Round 9
// baseline (489.888 us; speedup 1.0000x reference)
//
#include <hip/hip_runtime.h>
#include <hip/hip_bf16.h>

#define BB 4
#define CC 256
#define NN 4096
#define NSPLIT 4
#define KSPLIT (NN / NSPLIT)
#define NPAIR (KSPLIT / 64)

typedef __attribute__((ext_vector_type(8))) short short8;
typedef __attribute__((ext_vector_type(4))) float floatx4;
typedef __attribute__((ext_vector_type(4))) unsigned short ushortx4;

__device__ __forceinline__ float bf2f(unsigned short u) {
  union { unsigned int i; float f; } cv; cv.i = ((unsigned int)u) << 16; return cv.f;
}
__device__ __forceinline__ unsigned short f2bf(float f) {
  union { __hip_bfloat16 h; unsigned short u; } cv; cv.h = __float2bfloat16(f); return cv.u;
}

#define MFMA(a, b, c) __builtin_amdgcn_mfma_f32_16x16x32_bf16((a), (b), (c), 0, 0, 0)

// async global->LDS DMA, 16B/lane, LDS dest = wave-uniform base + lane*16
__device__ __forceinline__ void dma16(const unsigned short* g, unsigned short* l) {
  __builtin_amdgcn_global_load_lds(
      (const __attribute__((address_space(1))) unsigned int*)g,
      (__attribute__((address_space(3))) unsigned int*)l, 16, 0, 0);
}
#define S_BARRIER __builtin_amdgcn_s_barrier()
#define MEMFENCE __asm__ volatile("" ::: "memory")

// ---------------------------------------------------------------------------
// Phase 1 (fused): Xbf[b][n][c] = bf16(x[b][c][n] + PE(c,n)) via LDS
// transpose; first 192 blocks ALSO convert fp32 weights -> bf16.
// ---------------------------------------------------------------------------
__global__ __launch_bounds__(256) void prep_x(const float* __restrict__ x,
                                              const float* __restrict__ wq,
                                              const float* __restrict__ wk,
                                              const float* __restrict__ wv,
                                              unsigned short* __restrict__ Xbf,
                                              unsigned short* __restrict__ Wqk,
                                              unsigned short* __restrict__ Wv) {
  int tid = threadIdx.y * 32 + threadIdx.x;
  int gid = blockIdx.x + gridDim.x * (blockIdx.y + gridDim.y * blockIdx.z);
  if (gid < 192) {  // 192 x 1024 floats = 3 x 256 x 256
    int e = gid * 1024 + tid * 4;
    floatx4 v;
    unsigned short* dst;
    if (e < 65536) {
      v = *(const floatx4*)&wq[e];
      dst = &Wqk[e];
    } else if (e < 131072) {
      v = *(const floatx4*)&wk[e - 65536];
      dst = &Wqk[e];
    } else {
      v = *(const floatx4*)&wv[e - 131072];
      dst = &Wv[e - 131072];
    }
    ushortx4 p;
#pragma unroll
    for (int r = 0; r < 4; r++) p[r] = f2bf(v[r]);
    *(ushortx4*)dst = p;
  }

  __shared__ float tile[32][33];
  int b = blockIdx.z;
  int n0 = blockIdx.x * 32, c0 = blockIdx.y * 32;
  int tx = threadIdx.x, ty = threadIdx.y;
#pragma unroll
  for (int i = 0; i < 4; i++) {
    int c = c0 + ty + i * 8;
    int n = n0 + tx;
    float v = x[((long)(b * CC + c)) * NN + n];
    int hh = n >> 6, ww = n & 63;
    int j = c & 63;
    float freq = exp2f(-0.2076205059304601f * (float)j);  // 10000^(-j/64)
    float arg = (float)((c < 128) ? ww : hh) * freq;
    v += (c & 64) ? cosf(arg) : sinf(arg);
    tile[ty + i * 8][tx] = v;
  }
  __syncthreads();
#pragma unroll
  for (int i = 0; i < 4; i++) {
    int n = n0 + ty + i * 8;
    int c = c0 + tx;
    Xbf[((long)(b * NN + n)) * CC + c] = f2bf(tile[tx][ty + i * 8]);
  }
}

// ---------------------------------------------------------------------------
// Phase 2 (m97-class): fused 128x128-tile GEMM, C = A * Bt^T, K=256, bf16.
// Flat grid 768: F<512 -> QK = Xbf * Wqk^T; F>=512 -> Vt = Wv * Xbf^T.
// ---------------------------------------------------------------------------
__global__ __launch_bounds__(256, 2) void gemm_fused(const unsigned short* __restrict__ Xbf,
                                                     const unsigned short* __restrict__ Wqk,
                                                     const unsigned short* __restrict__ Wv,
                                                     unsigned short* __restrict__ QK,
                                                     unsigned short* __restrict__ Vt) {
  __shared__ alignas(16) unsigned short Af[2][8 * 512];
  __shared__ alignas(16) unsigned short Bf[2][8 * 512];
  const unsigned short *Ab, *Bb;
  unsigned short* Ob;
  long row0, col0;
  int ldo;
  int F = blockIdx.x;
  if (F < 512) {  // QK: A=Xbf(4096x256), Bt=Wqk(512x256), O=(B,N,512)
    int b = F >> 7, r = F & 127;
    row0 = (long)(r >> 2) * 128;
    col0 = (long)(r & 3) * 128;
    Ab = Xbf + (long)b * NN * CC;
    Bb = Wqk;
    Ob = QK + (long)b * NN * 512;
    ldo = 512;
  } else {  // Vt: A=Wv(256x256), Bt=Xbf(4096x256), O=(B,C,N)
    int F2 = F - 512;
    int b = F2 >> 6, r = F2 & 63;
    row0 = (long)(r >> 5) * 128;
    col0 = (long)(r & 31) * 128;
    Ab = Wv;
    Bb = Xbf + (long)b * NN * CC;
    Ob = Vt + (long)b * CC * NN;
    ldo = NN;
  }
  int t = threadIdx.x, wave = t >> 6, lane = t & 63, quad = lane >> 4, l15 = lane & 15;
  int wr = wave >> 1, wc = wave & 1;

  auto stage = [&](int k0, int buf) {
#pragma unroll
    for (int i = 0; i < 2; i++) {
      int fg = wave * 2 + i;  // 0..7, wave-uniform
      dma16(&Ab[(row0 + fg * 16 + l15) * 256 + k0 + quad * 8], &Af[buf][fg * 512]);
      dma16(&Bb[(col0 + fg * 16 + l15) * 256 + k0 + quad * 8], &Bf[buf][fg * 512]);
    }
  };

  floatx4 acc[4][4] = {};
  stage(0, 0);
  MEMFENCE;
#pragma unroll
  for (int ki = 0; ki < 8; ki++) {
    int buf = ki & 1;
    S_BARRIER;
    MEMFENCE;
    if (ki + 1 < 8) {
      stage((ki + 1) * 32, buf ^ 1);
      MEMFENCE;
      __builtin_amdgcn_s_waitcnt(0xF74);  // vmcnt(4)
    } else {
      __builtin_amdgcn_s_waitcnt(0xF70);  // vmcnt(0)
    }
    S_BARRIER;
    MEMFENCE;
    short8 af[4], bf[4];
#pragma unroll
    for (int i = 0; i < 4; i++) {
      af[i] = *(const short8*)&Af[buf][(wr * 4 + i) * 512 + lane * 8];
      bf[i] = *(const short8*)&Bf[buf][(wc * 4 + i) * 512 + lane * 8];
    }
#pragma unroll
    for (int i = 0; i < 4; i++)
#pragma unroll
      for (int j = 0; j < 4; j++) acc[i][j] = MFMA(af[i], bf[j], acc[i][j]);
  }

#pragma unroll
  for (int i = 0; i < 4; i++)
#pragma unroll
    for (int j = 0; j < 4; j++) {
      long col = col0 + (wc * 4 + j) * 16 + l15;
#pragma unroll
      for (int r = 0; r < 4; r++) {
        long row = row0 + (wr * 4 + i) * 16 + quad * 4 + r;
        Ob[row * (long)ldo + col] = f2bf(acc[i][j][r]);
      }
    }
}

// ---------------------------------------------------------------------------
// Phase 3: flash attention, no online max. 4 waves/WG, 64 q-rows/wave
// (4 q-blocks): each kf/vf LDS read feeds 4 MFMAs. 1 wave/SIMD, ~450 VGPRs
// (fits 512 budget, no spill through 450 per m08). Grid 256 = 1 WG/CU.
// 4-slot LDS ring, barriers per 64-key pair, vmcnt(16) prefetch overlap.
// ---------------------------------------------------------------------------
__global__ __launch_bounds__(256, 1) void attn(const unsigned short* __restrict__ QKg,
                                               const unsigned short* __restrict__ Vtg,
                                               unsigned short* __restrict__ Opart,
                                               float* __restrict__ Lp) {
  __shared__ alignas(16) unsigned short Kl[4 * 8192];   // 64 KB
  __shared__ alignas(16) unsigned short Vl[4 * 8192];   // 64 KB
  __shared__ alignas(16) unsigned short Plf[4][4][512]; // 16 KB: wave x qb
  int F = blockIdx.x;
  int c = F & 15, sp = c & 3, b = c >> 2;
  long q0 = (long)(F >> 4) * 256;
  int t = threadIdx.x, wave = t >> 6, lane = t & 63, quad = lane >> 4, l15 = lane & 15;
  const unsigned short* Qb = QKg + (long)b * NN * 512;
  const unsigned short* Kb = Qb + 256;
  const unsigned short* Vb = Vtg + (long)b * CC * NN;

  // Q fragments (A-layout) for 4 q-blocks of 16 rows; row stride 512
  short8 qf[4][8];
#pragma unroll
  for (int qb = 0; qb < 4; qb++) {
    long qrow = q0 + wave * 64 + qb * 16 + l15;
#pragma unroll
    for (int ks = 0; ks < 8; ks++)
      qf[qb][ks] = *(const short8*)&Qb[qrow * 512 + ks * 32 + quad * 8];
  }

  floatx4 acc[4][17] = {};  // [qb][0..15]=O d-blocks, [16]=l (ones column)
  short8 ones;
#pragma unroll
  for (int j = 0; j < 8; j++) ones[j] = (short)0x3F80;  // bf16 1.0

  const float sc = 0.0625f * 1.4426950408889634f;  // scale * log2(e)
  const int kbeg = sp * KSPLIT;

  // stage pair p (2 tiles x 32 keys); 16 DMAs per wave
  auto stage_pair = [&](int p, int buf) {
#pragma unroll
    for (int tt = 0; tt < 2; tt++) {
      int m0 = kbeg + (p * 2 + tt) * 32;
      int slot = buf * 2 + tt;
#pragma unroll
      for (int st = 0; st < 4; st++) {
        int fg = st * 4 + wave;  // wave-uniform, 0..15
        dma16(&Kb[(long)(m0 + (fg >> 3) * 16 + l15) * 512 + (fg & 7) * 32 + quad * 8],
              &Kl[slot * 8192 + fg * 512]);
        dma16(&Vb[(long)(fg * 16 + l15) * NN + m0 + quad * 8],
              &Vl[slot * 8192 + fg * 512]);
      }
    }
  };

  __builtin_amdgcn_s_waitcnt(0xF70);  // drain Q loads so vmcnt tracks DMAs only
  stage_pair(0, 0);
  MEMFENCE;

  for (int p = 0; p < NPAIR; p++) {
    int buf = p & 1;
    S_BARRIER;  // all waves done reading ring half buf^1 -> overwrite ok
    MEMFENCE;
    if (p + 1 < NPAIR) {
      stage_pair(p + 1, buf ^ 1);
      MEMFENCE;
      __builtin_amdgcn_s_waitcnt(0x4F70);  // vmcnt(16): pair-p DMAs done
    } else {
      __builtin_amdgcn_s_waitcnt(0xF70);  // vmcnt(0)
    }
    S_BARRIER;  // pair-p data visible to all waves
    MEMFENCE;

#pragma unroll
    for (int tt = 0; tt < 2; tt++) {
      int kb = (buf * 2 + tt) * 8192;
      // S = Q K^T : 4 q-blocks x 32 keys; each kf read feeds 4 MFMAs
      floatx4 s[4][2];
#pragma unroll
      for (int qb = 0; qb < 4; qb++) {
        floatx4 z = {0.f, 0.f, 0.f, 0.f};
        s[qb][0] = z;
        s[qb][1] = z;
      }
#pragma unroll
      for (int fgk = 0; fgk < 16; fgk++) {
        short8 kf = *(const short8*)&Kl[kb + fgk * 512 + lane * 8];
        int mt = fgk >> 3, ks = fgk & 7;
#pragma unroll
        for (int qb = 0; qb < 4; qb++) s[qb][mt] = MFMA(qf[qb][ks], kf, s[qb][mt]);
      }

      // p = 2^(s*sc) (no max shift: |s*sc| <= ~35 log2-units, safe in fp32)
#pragma unroll
      for (int qb = 0; qb < 4; qb++) {
#pragma unroll
        for (int r = 0; r < 4; r++) {
          unsigned short pb0 = f2bf(__builtin_amdgcn_exp2f(s[qb][0][r] * sc));
          unsigned short pb1 = f2bf(__builtin_amdgcn_exp2f(s[qb][1][r] * sc));
          int m = quad * 4 + r;
          Plf[wave][qb][((l15 >> 3) * 16 + m) * 8 + (l15 & 7)] = pb0;        // k=l15
          Plf[wave][qb][((2 + (l15 >> 3)) * 16 + m) * 8 + (l15 & 7)] = pb1;  // k=16+l15
        }
      }
      MEMFENCE;  // P writes before same-wave A-frag re-read (HW DS in-order)
      short8 pf[4];
#pragma unroll
      for (int qb = 0; qb < 4; qb++) {
        pf[qb] = *(const short8*)&Plf[wave][qb][lane * 8];
        acc[qb][16] = MFMA(pf[qb], ones, acc[qb][16]);  // l row-sums
      }
#pragma unroll
      for (int db = 0; db < 16; db++) {
        short8 vf = *(const short8*)&Vl[kb + db * 512 + lane * 8];
#pragma unroll
        for (int qb = 0; qb < 4; qb++) acc[qb][db] = MFMA(pf[qb], vf, acc[qb][db]);
      }
      MEMFENCE;  // next tile's P writes stay after this tile's pf reads
    }
  }

  // epilogue: unnormalized partial O (scale 2^0) + per-row l
  unsigned short* Ob = Opart + (long)(b * NSPLIT + sp) * CC * NN;
#pragma unroll
  for (int qb = 0; qb < 4; qb++) {
    long nidx = q0 + wave * 64 + qb * 16 + quad * 4;
#pragma unroll
    for (int db = 0; db < 16; db++) {
      long d = db * 16 + l15;
      ushortx4 pk;
#pragma unroll
      for (int r = 0; r < 4; r++) pk[r] = f2bf(acc[qb][db][r]);
      *(ushortx4*)&Ob[d * NN + nidx] = pk;
    }
    if (l15 == 0) {
#pragma unroll
      for (int r = 0; r < 4; r++)
        Lp[(long)(b * NSPLIT + sp) * NN + nidx + r] = acc[qb][16][r];
    }
  }
}

// ---------------------------------------------------------------------------
// Phase 4: combine = sum partials, divide by total l. Block = 64 d x 64 n.
// ---------------------------------------------------------------------------
__global__ __launch_bounds__(256) void combine(const unsigned short* __restrict__ Op,
                                               const float* __restrict__ Lp,
                                               float* __restrict__ Out) {
  __shared__ float Wl[64];
  int b = blockIdx.z;
  int d0 = blockIdx.y * 64, n0 = blockIdx.x * 64;
  int t = threadIdx.x;
  if (t < 64) {
    int n = n0 + t;
    float L = 0.f;
#pragma unroll
    for (int s = 0; s < NSPLIT; s++) L += Lp[(long)(b * NSPLIT + s) * NN + n];
    Wl[t] = 1.0f / L;
  }
  __syncthreads();
  int tn = t & 15, td = t >> 4;
  int nb = n0 + tn * 4;
  float w[4];
#pragma unroll
  for (int r = 0; r < 4; r++) w[r] = Wl[tn * 4 + r];
#pragma unroll
  for (int dd = 0; dd < 4; dd++) {
    int d = d0 + td * 4 + dd;
    floatx4 o = {0.f, 0.f, 0.f, 0.f};
#pragma unroll
    for (int s = 0; s < NSPLIT; s++) {
      ushortx4 pv = *(const ushortx4*)&Op[((long)(b * NSPLIT + s) * CC + d) * NN + nb];
#pragma unroll
      for (int r = 0; r < 4; r++) o[r] += bf2f(pv[r]);
    }
#pragma unroll
    for (int r = 0; r < 4; r++) o[r] *= w[r];
    *(floatx4*)&Out[((long)b * CC + d) * NN + nb] = o;
  }
}

// ---------------------------------------------------------------------------
extern "C" void kernel_launch(void* const* d_in, const int* in_sizes, int n_in,
                              void* d_out, int out_size, void* d_ws, size_t ws_size,
                              hipStream_t stream) {
  const float* x = (const float*)d_in[0];
  const float* wq = (const float*)d_in[1];
  const float* wk = (const float*)d_in[2];
  const float* wv = (const float*)d_in[3];
  float* out = (float*)d_out;

  char* ws = (char*)d_ws;
  unsigned short* QKbuf = (unsigned short*)(ws);             // 16 MB (B,N,512)
  unsigned short* Vt = (unsigned short*)(ws + (16l << 20));  // 8 MB (B,C,N)
  unsigned short* Xbf = (unsigned short*)(ws + (24l << 20));   // 8 MB (dead after gemm)
  unsigned short* Opart = (unsigned short*)(ws + (24l << 20)); // 32 MB (B,S,C,N)
  float* Lp = (float*)(ws + (56l << 20));                      // 256 KB
  unsigned short* Wqk = (unsigned short*)(ws + (57l << 20));   // 256 KB (512x256)
  unsigned short* Wv = (unsigned short*)(ws + (57l << 20) + (1 << 19));  // 128 KB

  prep_x<<<dim3(NN / 32, CC / 32, BB), dim3(32, 8), 0, stream>>>(x, wq, wk, wv, Xbf,
                                                                 Wqk, Wv);
  gemm_fused<<<dim3(768), 256, 0, stream>>>(Xbf, Wqk, Wv, QKbuf, Vt);
  attn<<<dim3(256), 256, 0, stream>>>(QKbuf, Vt, Opart, Lp);
  combine<<<dim3(NN / 64, CC / 64, BB), 256, 0, stream>>>(Opart, Lp, out);
}

// Round 10
// 197.393 us; speedup vs baseline: 2.4818x; 2.4818x over previous
//
#include <hip/hip_runtime.h>
#include <hip/hip_bf16.h>

#define BB 4
#define CC 256
#define NN 4096
#define NSPLIT 4
#define KSPLIT (NN / NSPLIT)
#define NPAIR (KSPLIT / 64)

typedef __attribute__((ext_vector_type(8))) short short8;
typedef __attribute__((ext_vector_type(4))) float floatx4;
typedef __attribute__((ext_vector_type(4))) unsigned short ushortx4;

__device__ __forceinline__ float bf2f(unsigned short u) {
  union { unsigned int i; float f; } cv; cv.i = ((unsigned int)u) << 16; return cv.f;
}
__device__ __forceinline__ unsigned short f2bf(float f) {
  union { __hip_bfloat16 h; unsigned short u; } cv; cv.h = __float2bfloat16(f); return cv.u;
}

#define MFMA(a, b, c) __builtin_amdgcn_mfma_f32_16x16x32_bf16((a), (b), (c), 0, 0, 0)

// async global->LDS DMA, 16B/lane, LDS dest = wave-uniform base + lane*16
__device__ __forceinline__ void dma16(const unsigned short* g, unsigned short* l) {
  __builtin_amdgcn_global_load_lds(
      (const __attribute__((address_space(1))) unsigned int*)g,
      (__attribute__((address_space(3))) unsigned int*)l, 16, 0, 0);
}
#define S_BARRIER __builtin_amdgcn_s_barrier()
#define MEMFENCE __asm__ volatile("" ::: "memory")

// ---------------------------------------------------------------------------
// Phase 1 (fused): Xbf[b][n][c] = bf16(x[b][c][n] + PE(c,n)) via LDS
// transpose; first 192 blocks ALSO convert fp32 weights -> bf16.
// ---------------------------------------------------------------------------
__global__ __launch_bounds__(256) void prep_x(const float* __restrict__ x,
                                              const float* __restrict__ wq,
                                              const float* __restrict__ wk,
                                              const float* __restrict__ wv,
                                              unsigned short* __restrict__ Xbf,
                                              unsigned short* __restrict__ Wqk,
                                              unsigned short* __restrict__ Wv) {
  int tid = threadIdx.y * 32 + threadIdx.x;
  int gid = blockIdx.x + gridDim.x * (blockIdx.y + gridDim.y * blockIdx.z);
  if (gid < 192) {  // 192 x 1024 floats = 3 x 256 x 256
    int e = gid * 1024 + tid * 4;
    floatx4 v;
    unsigned short* dst;
    if (e < 65536) {
      v = *(const floatx4*)&wq[e];
      dst = &Wqk[e];
    } else if (e < 131072) {
      v = *(const floatx4*)&wk[e - 65536];
      dst = &Wqk[e];
    } else {
      v = *(const floatx4*)&wv[e - 131072];
      dst = &Wv[e - 131072];
    }
    ushortx4 p;
#pragma unroll
    for (int r = 0; r < 4; r++) p[r] = f2bf(v[r]);
    *(ushortx4*)dst = p;
  }

  __shared__ float tile[32][33];
  int b = blockIdx.z;
  int n0 = blockIdx.x * 32, c0 = blockIdx.y * 32;
  int tx = threadIdx.x, ty = threadIdx.y;
#pragma unroll
  for (int i = 0; i < 4; i++) {
    int c = c0 + ty + i * 8;
    int n = n0 + tx;
    float v = x[((long)(b * CC + c)) * NN + n];
    int hh = n >> 6, ww = n & 63;
    int j = c & 63;
    float freq = exp2f(-0.2076205059304601f * (float)j);  // 10000^(-j/64)
    float arg = (float)((c < 128) ? ww : hh) * freq;
    v += (c & 64) ? cosf(arg) : sinf(arg);
    tile[ty + i * 8][tx] = v;
  }
  __syncthreads();
#pragma unroll
  for (int i = 0; i < 4; i++) {
    int n = n0 + ty + i * 8;
    int c = c0 + tx;
    Xbf[((long)(b * NN + n)) * CC + c] = f2bf(tile[tx][ty + i * 8]);
  }
}

// ---------------------------------------------------------------------------
// Phase 2 (m97-class): fused 128x128-tile GEMM, C = A * Bt^T, K=256, bf16.
// Flat grid 768: F<512 -> QK = Xbf * Wqk^T; F>=512 -> Vt = Wv * Xbf^T.
// ---------------------------------------------------------------------------
__global__ __launch_bounds__(256, 2) void gemm_fused(const unsigned short* __restrict__ Xbf,
                                                     const unsigned short* __restrict__ Wqk,
                                                     const unsigned short* __restrict__ Wv,
                                                     unsigned short* __restrict__ QK,
                                                     unsigned short* __restrict__ Vt) {
  __shared__ alignas(16) unsigned short Af[2][8 * 512];
  __shared__ alignas(16) unsigned short Bf[2][8 * 512];
  const unsigned short *Ab, *Bb;
  unsigned short* Ob;
  long row0, col0;
  int ldo;
  int F = blockIdx.x;
  if (F < 512) {  // QK: A=Xbf(4096x256), Bt=Wqk(512x256), O=(B,N,512)
    int b = F >> 7, r = F & 127;
    row0 = (long)(r >> 2) * 128;
    col0 = (long)(r & 3) * 128;
    Ab = Xbf + (long)b * NN * CC;
    Bb = Wqk;
    Ob = QK + (long)b * NN * 512;
    ldo = 512;
  } else {  // Vt: A=Wv(256x256), Bt=Xbf(4096x256), O=(B,C,N)
    int F2 = F - 512;
    int b = F2 >> 6, r = F2 & 63;
    row0 = (long)(r >> 5) * 128;
    col0 = (long)(r & 31) * 128;
    Ab = Wv;
    Bb = Xbf + (long)b * NN * CC;
    Ob = Vt + (long)b * CC * NN;
    ldo = NN;
  }
  int t = threadIdx.x, wave = t >> 6, lane = t & 63, quad = lane >> 4, l15 = lane & 15;
  int wr = wave >> 1, wc = wave & 1;

  auto stage = [&](int k0, int buf) {
#pragma unroll
    for (int i = 0; i < 2; i++) {
      int fg = wave * 2 + i;  // 0..7, wave-uniform
      dma16(&Ab[(row0 + fg * 16 + l15) * 256 + k0 + quad * 8], &Af[buf][fg * 512]);
      dma16(&Bb[(col0 + fg * 16 + l15) * 256 + k0 + quad * 8], &Bf[buf][fg * 512]);
    }
  };

  floatx4 acc[4][4] = {};
  stage(0, 0);
  MEMFENCE;
#pragma unroll
  for (int ki = 0; ki < 8; ki++) {
    int buf = ki & 1;
    S_BARRIER;
    MEMFENCE;
    if (ki + 1 < 8) {
      stage((ki + 1) * 32, buf ^ 1);
      MEMFENCE;
      __builtin_amdgcn_s_waitcnt(0xF74);  // vmcnt(4)
    } else {
      __builtin_amdgcn_s_waitcnt(0xF70);  // vmcnt(0)
    }
    S_BARRIER;
    MEMFENCE;
    short8 af[4], bf[4];
#pragma unroll
    for (int i = 0; i < 4; i++) {
      af[i] = *(const short8*)&Af[buf][(wr * 4 + i) * 512 + lane * 8];
      bf[i] = *(const short8*)&Bf[buf][(wc * 4 + i) * 512 + lane * 8];
    }
#pragma unroll
    for (int i = 0; i < 4; i++)
#pragma unroll
      for (int j = 0; j < 4; j++) acc[i][j] = MFMA(af[i], bf[j], acc[i][j]);
  }

#pragma unroll
  for (int i = 0; i < 4; i++)
#pragma unroll
    for (int j = 0; j < 4; j++) {
      long col = col0 + (wc * 4 + j) * 16 + l15;
#pragma unroll
      for (int r = 0; r < 4; r++) {
        long row = row0 + (wr * 4 + i) * 16 + quad * 4 + r;
        Ob[row * (long)ldo + col] = f2bf(acc[i][j][r]);
      }
    }
}

// ---------------------------------------------------------------------------
// Phase 3: flash attention, no online max. R7 geometry (8 waves, 2 qb/wave,
// grid 256 = 1 WG/CU, 4-slot ring, vmcnt(8) prefetch) with a RESTRUCTURED
// pair body: QK0 -> exp0+Pwrite0 -> QK1 (no fence: covers P roundtrip) ->
// FENCE -> pf0+PV0 -> exp1+Pwrite1 -> FENCE -> pf1+PV1. Two fences per pair
// (was four); tile1's 32 QK MFMAs hide tile0's exp2 + LDS latency.
// acc cap respected: 34 floatx4 accumulators per wave (<= 64 limit).
// ---------------------------------------------------------------------------
__global__ __launch_bounds__(512, 1) void attn(const unsigned short* __restrict__ QKg,
                                               const unsigned short* __restrict__ Vtg,
                                               unsigned short* __restrict__ Opart,
                                               float* __restrict__ Lp) {
  __shared__ alignas(16) unsigned short Kl[4 * 8192];   // 64 KB
  __shared__ alignas(16) unsigned short Vl[4 * 8192];   // 64 KB
  __shared__ alignas(16) unsigned short Plf[8][2][512]; // 16 KB
  int F = blockIdx.x;
  int c = F & 15, sp = c & 3, b = c >> 2;
  long q0 = (long)(F >> 4) * 256;
  int t = threadIdx.x, wave = t >> 6, lane = t & 63, quad = lane >> 4, l15 = lane & 15;
  const unsigned short* Qb = QKg + (long)b * NN * 512;
  const unsigned short* Kb = Qb + 256;
  const unsigned short* Vb = Vtg + (long)b * CC * NN;

  short8 qf[2][8];
#pragma unroll
  for (int qb = 0; qb < 2; qb++) {
    long qrow = q0 + wave * 32 + qb * 16 + l15;
#pragma unroll
    for (int ks = 0; ks < 8; ks++)
      qf[qb][ks] = *(const short8*)&Qb[qrow * 512 + ks * 32 + quad * 8];
  }

  floatx4 acc[2][17] = {};  // 34 floatx4 = 136 acc regs (within 256-cap)
  short8 ones;
#pragma unroll
  for (int j = 0; j < 8; j++) ones[j] = (short)0x3F80;  // bf16 1.0

  const float sc = 0.0625f * 1.4426950408889634f;  // scale * log2(e)
  const int kbeg = sp * KSPLIT;

  auto stage_pair = [&](int p, int buf) {
#pragma unroll
    for (int tt = 0; tt < 2; tt++) {
      int m0 = kbeg + (p * 2 + tt) * 32;
      int slot = buf * 2 + tt;
#pragma unroll
      for (int st = 0; st < 2; st++) {
        int fg = st * 8 + wave;  // wave-uniform, 0..15
        dma16(&Kb[(long)(m0 + st * 16 + l15) * 512 + wave * 32 + quad * 8],
              &Kl[slot * 8192 + fg * 512]);
        dma16(&Vb[(long)(fg * 16 + l15) * NN + m0 + quad * 8],
              &Vl[slot * 8192 + fg * 512]);
      }
    }
  };

  // per-tile helpers --------------------------------------------------------
  auto qk = [&](int kb, floatx4 s[2][2]) {
#pragma unroll
    for (int qb = 0; qb < 2; qb++) {
      floatx4 z = {0.f, 0.f, 0.f, 0.f};
      s[qb][0] = z;
      s[qb][1] = z;
    }
#pragma unroll
    for (int fgk = 0; fgk < 16; fgk++) {
      short8 kf = *(const short8*)&Kl[kb + fgk * 512 + lane * 8];
      int mt = fgk >> 3, ks = fgk & 7;
      s[0][mt] = MFMA(qf[0][ks], kf, s[0][mt]);
      s[1][mt] = MFMA(qf[1][ks], kf, s[1][mt]);
    }
  };
  auto expwr = [&](floatx4 s[2][2]) {
#pragma unroll
    for (int qb = 0; qb < 2; qb++) {
#pragma unroll
      for (int r = 0; r < 4; r++) {
        unsigned short pb0 = f2bf(__builtin_amdgcn_exp2f(s[qb][0][r] * sc));
        unsigned short pb1 = f2bf(__builtin_amdgcn_exp2f(s[qb][1][r] * sc));
        int m = quad * 4 + r;
        Plf[wave][qb][((l15 >> 3) * 16 + m) * 8 + (l15 & 7)] = pb0;        // k=l15
        Plf[wave][qb][((2 + (l15 >> 3)) * 16 + m) * 8 + (l15 & 7)] = pb1;  // k=16+l15
      }
    }
  };
  auto pv = [&](int kb) {
    short8 pf0 = *(const short8*)&Plf[wave][0][lane * 8];
    short8 pf1 = *(const short8*)&Plf[wave][1][lane * 8];
    acc[0][16] = MFMA(pf0, ones, acc[0][16]);  // l row-sums
    acc[1][16] = MFMA(pf1, ones, acc[1][16]);
#pragma unroll
    for (int db = 0; db < 16; db++) {
      short8 vf = *(const short8*)&Vl[kb + db * 512 + lane * 8];
      acc[0][db] = MFMA(pf0, vf, acc[0][db]);
      acc[1][db] = MFMA(pf1, vf, acc[1][db]);
    }
  };

  __builtin_amdgcn_s_waitcnt(0xF70);  // drain Q loads so vmcnt tracks DMAs only
  stage_pair(0, 0);
  MEMFENCE;

  for (int p = 0; p < NPAIR; p++) {
    int buf = p & 1;
    S_BARRIER;  // all waves done reading ring half buf^1 -> overwrite ok
    MEMFENCE;
    if (p + 1 < NPAIR) {
      stage_pair(p + 1, buf ^ 1);
      MEMFENCE;
      __builtin_amdgcn_s_waitcnt(0xF78);  // vmcnt(8): pair-p DMAs done
    } else {
      __builtin_amdgcn_s_waitcnt(0xF70);  // vmcnt(0)
    }
    S_BARRIER;  // pair-p data visible to all waves
    MEMFENCE;

    int kb0 = (buf * 2) * 8192, kb1 = kb0 + 8192;
    floatx4 s[2][2];
    qk(kb0, s);    // tile0 scores
    expwr(s);      // tile0 P -> LDS (per-wave buffer)
    qk(kb1, s);    // tile1 scores (reuses s; no fence: overlaps P roundtrip)
    MEMFENCE;      // P0 writes complete-before pf0 reads (compiler order)
    pv(kb0);       // tile0 PV
    expwr(s);      // tile1 P -> same LDS buffer (after pf0 reads: in-order DS)
    MEMFENCE;      // P1 writes before pf1 reads
    pv(kb1);       // tile1 PV
  }

  // epilogue: unnormalized partial O (scale 2^0) + per-row l
  unsigned short* Ob = Opart + (long)(b * NSPLIT + sp) * CC * NN;
#pragma unroll
  for (int qb = 0; qb < 2; qb++) {
    long nidx = q0 + wave * 32 + qb * 16 + quad * 4;
#pragma unroll
    for (int db = 0; db < 16; db++) {
      long d = db * 16 + l15;
      ushortx4 pk;
#pragma unroll
      for (int r = 0; r < 4; r++) pk[r] = f2bf(acc[qb][db][r]);
      *(ushortx4*)&Ob[d * NN + nidx] = pk;
    }
    if (l15 == 0) {
#pragma unroll
      for (int r = 0; r < 4; r++)
        Lp[(long)(b * NSPLIT + sp) * NN + nidx + r] = acc[qb][16][r];
    }
  }
}

// ---------------------------------------------------------------------------
// Phase 4: combine = sum partials, divide by total l. Block = 64 d x 64 n.
// ---------------------------------------------------------------------------
__global__ __launch_bounds__(256) void combine(const unsigned short* __restrict__ Op,
                                               const float* __restrict__ Lp,
                                               float* __restrict__ Out) {
  __shared__ float Wl[64];
  int b = blockIdx.z;
  int d0 = blockIdx.y * 64, n0 = blockIdx.x * 64;
  int t = threadIdx.x;
  if (t < 64) {
    int n = n0 + t;
    float L = 0.f;
#pragma unroll
    for (int s = 0; s < NSPLIT; s++) L += Lp[(long)(b * NSPLIT + s) * NN + n];
    Wl[t] = 1.0f / L;
  }
  __syncthreads();
  int tn = t & 15, td = t >> 4;
  int nb = n0 + tn * 4;
  float w[4];
#pragma unroll
  for (int r = 0; r < 4; r++) w[r] = Wl[tn * 4 + r];
#pragma unroll
  for (int dd = 0; dd < 4; dd++) {
    int d = d0 + td * 4 + dd;
    floatx4 o = {0.f, 0.f, 0.f, 0.f};
#pragma unroll
    for (int s = 0; s < NSPLIT; s++) {
      ushortx4 pv = *(const ushortx4*)&Op[((long)(b * NSPLIT + s) * CC + d) * NN + nb];
#pragma unroll
      for (int r = 0; r < 4; r++) o[r] += bf2f(pv[r]);
    }
#pragma unroll
    for (int r = 0; r < 4; r++) o[r] *= w[r];
    *(floatx4*)&Out[((long)b * CC + d) * NN + nb] = o;
  }
}

// ---------------------------------------------------------------------------
extern "C" void kernel_launch(void* const* d_in, const int* in_sizes, int n_in,
                              void* d_out, int out_size, void* d_ws, size_t ws_size,
                              hipStream_t stream) {
  const float* x = (const float*)d_in[0];
  const float* wq = (const float*)d_in[1];
  const float* wk = (const float*)d_in[2];
  const float* wv = (const float*)d_in[3];
  float* out = (float*)d_out;

  char* ws = (char*)d_ws;
  unsigned short* QKbuf = (unsigned short*)(ws);             // 16 MB (B,N,512)
  unsigned short* Vt = (unsigned short*)(ws + (16l << 20));  // 8 MB (B,C,N)
  unsigned short* Xbf = (unsigned short*)(ws + (24l << 20));   // 8 MB (dead after gemm)
  unsigned short* Opart = (unsigned short*)(ws + (24l << 20)); // 32 MB (B,S,C,N)
  float* Lp = (float*)(ws + (56l << 20));                      // 256 KB
  unsigned short* Wqk = (unsigned short*)(ws + (57l << 20));   // 256 KB (512x256)
  unsigned short* Wv = (unsigned short*)(ws + (57l << 20) + (1 << 19));  // 128 KB

  prep_x<<<dim3(NN / 32, CC / 32, BB), dim3(32, 8), 0, stream>>>(x, wq, wk, wv, Xbf,
                                                                 Wqk, Wv);
  gemm_fused<<<dim3(768), 256, 0, stream>>>(Xbf, Wqk, Wv, QKbuf, Vt);
  attn<<<dim3(256), 512, 0, stream>>>(QKbuf, Vt, Opart, Lp);
  combine<<<dim3(NN / 64, CC / 64, BB), 256, 0, stream>>>(Opart, Lp, out);
}